// Round 15
// baseline (455.927 us; speedup 1.0000x reference)
//
#include <hip/hip_runtime.h>

#define D_MODEL 1024
#define NH 16
#define DKH 64
#define SEQ 2048
#define BATCH 4
#define ROWS (BATCH*SEQ)

typedef _Float16 f16;
typedef _Float16 f16x4 __attribute__((ext_vector_type(4)));
typedef _Float16 f16x8 __attribute__((ext_vector_type(8)));
typedef float f32x4 __attribute__((ext_vector_type(4)));

#define MFMA16(a,b,c) __builtin_amdgcn_mfma_f32_16x16x32_f16((a),(b),(c),0,0,0)
#define CFENCE() asm volatile("" ::: "memory")

__device__ __forceinline__ void gload16(const void* g, void* l) {
  __builtin_amdgcn_global_load_lds((const __attribute__((address_space(1))) void*)g,
                                   (__attribute__((address_space(3))) void*)l,
                                   16, 0, 0);
}

// ---------------- weight transpose/convert ----------------

__global__ __launch_bounds__(256) void cvt_w_kernel(const float* __restrict__ Wq,
    const float* __restrict__ Wk, const float* __restrict__ Wv, const float* __restrict__ Wo,
    f16* __restrict__ dst)
{
  const float* W = (blockIdx.z==0)?Wq:(blockIdx.z==1)?Wk:(blockIdx.z==2)?Wv:Wo;
  f16* d = dst + (size_t)blockIdx.z * ((size_t)D_MODEL*D_MODEL);
  int idx = blockIdx.x*256 + threadIdx.x;
  int k = idx>>10, n = idx&1023;
  d[(size_t)n*D_MODEL + k] = (f16)W[idx];   // store W^T: [n][k]
}

// ---------------- 128x128 MFMA GEMM (R14-identical) ----------------

template<int AF32>
__global__ __launch_bounds__(256) void gemm128(
    const void* __restrict__ A0, const void* __restrict__ A1, const void* __restrict__ A2,
    const f16* __restrict__ WTbase,
    const float* __restrict__ bias0, const float* __restrict__ bias1, const float* __restrict__ bias2,
    f16* __restrict__ out0, f16* __restrict__ out1, f16* __restrict__ out2,
    const float* __restrict__ resid, float* __restrict__ xout, int modeBase)
{
  __shared__ __align__(128) char ldsb[49152];
  const int t = threadIdx.x, w = t>>6, l = t&63;
  const int nwg = (int)gridDim.x;
  const int wg = ((int)blockIdx.x & 7) * (nwg >> 3) + ((int)blockIdx.x >> 3);
  const int z  = wg >> 9;            // 512 blocks per mode
  const int r2 = wg & 511;
  const int bm = r2 >> 3, bn = r2 & 7;
  const int mode = modeBase + z;
  const f16* WT = WTbase + (size_t)mode * ((size_t)D_MODEL*D_MODEL);
  const float* bias = (mode==0)?bias0:(mode==1)?bias1:(mode==2)?bias2:bias0;
  const int wm = w>>1, wn = w&1;
  const int lr = l>>2, lc = l&3, fr = l&15, fg = l>>4;
  f32x4 acc[4][4] = {};
  const char* Bb = (const char*)(WT + (size_t)bn*128*D_MODEL);

#define BAR_FENCED() do { __builtin_amdgcn_s_barrier(); CFENCE(); } while(0)

  if constexpr (AF32) {
    const float* A32 = (const float*)((z==0)?A0:(z==1)?A1:A2);
    const char* Ag = (const char*)A32 + ((size_t)(bm*128 + (t>>3)) * 4096)
                     + (size_t)(((t&7) ^ ((t>>3)&7)) << 4);
    const int su0 = (((fg*2)   ^ (fr&7)) << 4);
    const int su1 = (((fg*2+1) ^ (fr&7)) << 4);

#define STAGEA32(bufv, ktv) do { \
    _Pragma("unroll") \
    for (int cc=0; cc<4; ++cc) \
      gload16(Ag + (size_t)cc*131072 + (size_t)(ktv)*128, ldsb + (bufv)*16384 + cc*4096 + t*16); \
  } while(0)

#define STAGEB32(bufv, ktv) do { \
    char* Bd = ldsb + 32768 + (bufv)*8192; \
    _Pragma("unroll") \
    for (int cc=0; cc<2; ++cc) { \
      int r0 = w*32 + cc*16; \
      gload16(Bb + (size_t)(r0+lr)*2048 + (ktv)*64 + lc*16, Bd + r0*64); \
    } \
  } while(0)

#define COMPUTE32(bufv) do { \
    const char* Abl = ldsb + (bufv)*16384; \
    const f16* Bc = (const f16*)(ldsb + 32768 + (bufv)*8192); \
    f16x8 a[4], b[4]; \
    _Pragma("unroll") \
    for (int i=0;i<4;++i) { \
      const char* rb = Abl + (wm*64 + i*16 + fr)*128; \
      f32x4 lo = *(const f32x4*)(rb + su0); \
      f32x4 hi = *(const f32x4*)(rb + su1); \
      f16x8 t8; \
      _Pragma("unroll") \
      for (int m2=0;m2<4;++m2) { t8[m2] = (f16)lo[m2]; t8[4+m2] = (f16)hi[m2]; } \
      a[i] = t8; \
    } \
    _Pragma("unroll") \
    for (int j=0;j<4;++j) b[j] = *(const f16x8*)(Bc + (wn*64+j*16+fr)*32 + fg*8); \
    _Pragma("unroll") \
    for (int i=0;i<4;++i) \
      _Pragma("unroll") \
      for (int j=0;j<4;++j) \
        acc[i][j] = MFMA16(a[i], b[j], acc[i][j]); \
  } while(0)

    STAGEA32(0, 0); STAGEB32(0, 0);
    CFENCE();
    for (int kt=0; kt<31; ++kt) {
      const int cur = kt & 1;
      STAGEA32(cur^1, kt+1);
      STAGEB32(cur^1, kt+1);
      asm volatile("s_waitcnt vmcnt(6)" ::: "memory");
      BAR_FENCED();
      COMPUTE32(cur);
      CFENCE();
      BAR_FENCED();
    }
    asm volatile("s_waitcnt vmcnt(0)" ::: "memory");
    BAR_FENCED();
    COMPUTE32(1);

#undef STAGEA32
#undef STAGEB32
#undef COMPUTE32
  } else {
    const char* Ab = (const char*)((const f16*)A0 + (size_t)bm*128*D_MODEL);

#define STAGE16(bufv, ktv) do { \
    char* Ad = ldsb + (bufv)*8192; \
    char* Bd = ldsb + 24576 + (bufv)*8192; \
    _Pragma("unroll") \
    for (int cc=0; cc<2; ++cc) { \
      int r0 = w*32 + cc*16; \
      gload16(Ab + (size_t)(r0+lr)*2048 + (ktv)*64 + lc*16, Ad + r0*64); \
      gload16(Bb + (size_t)(r0+lr)*2048 + (ktv)*64 + lc*16, Bd + r0*64); \
    } \
  } while(0)

#define COMPUTE16(bufv) do { \
    const f16* Ac = (const f16*)(ldsb + (bufv)*8192); \
    const f16* Bc = (const f16*)(ldsb + 24576 + (bufv)*8192); \
    f16x8 a[4], b[4]; \
    _Pragma("unroll") \
    for (int i=0;i<4;++i) a[i] = *(const f16x8*)(Ac + (wm*64+i*16+fr)*32 + fg*8); \
    _Pragma("unroll") \
    for (int j=0;j<4;++j) b[j] = *(const f16x8*)(Bc + (wn*64+j*16+fr)*32 + fg*8); \
    _Pragma("unroll") \
    for (int i=0;i<4;++i) \
      _Pragma("unroll") \
      for (int j=0;j<4;++j) \
        acc[i][j] = MFMA16(a[i], b[j], acc[i][j]); \
  } while(0)

    STAGE16(0, 0); STAGE16(1, 1);
    CFENCE();
    for (int kt=0; kt<30; ++kt) {
      STAGE16((kt+2)%3, kt+2);
      asm volatile("s_waitcnt vmcnt(8)" ::: "memory");
      BAR_FENCED();
      COMPUTE16(kt%3);
      CFENCE();
      BAR_FENCED();
    }
    asm volatile("s_waitcnt vmcnt(4)" ::: "memory");
    BAR_FENCED();
    COMPUTE16(0);     // kt=30
    CFENCE();
    BAR_FENCED();
    asm volatile("s_waitcnt vmcnt(0)" ::: "memory");
    BAR_FENCED();
    COMPUTE16(1);     // kt=31

#undef STAGE16
#undef COMPUTE16
  }

#undef BAR_FENCED

  #pragma unroll
  for (int j=0;j<4;++j) {
    int col = bn*128 + wn*64 + j*16 + fr;
    float bz = bias[col];
    #pragma unroll
    for (int i=0;i<4;++i) {
      int row0 = bm*128 + wm*64 + i*16 + fg*4;
      f32x4 v = acc[i][j];
      if (mode==0) {
        int hh = col>>6, dk = col&63;
        #pragma unroll
        for (int r=0;r<4;++r) {
          int row = row0+r; int b_ = row>>11, s = row&(SEQ-1);
          out0[((size_t)(b_*NH+hh)*SEQ + s)*DKH + dk] = (f16)((v[r]+bz)*0.125f);
        }
      } else if (mode==1) {
        int hh = col>>6, dk = col&63;
        #pragma unroll
        for (int r=0;r<4;++r) {
          int row = row0+r; int b_ = row>>11, s = row&(SEQ-1);
          out1[((size_t)(b_*NH+hh)*SEQ + s)*DKH + dk] = (f16)(v[r]+bz);
        }
      } else if (mode==2) {
        int hh = col>>6, dk = col&63;
        int b_ = row0>>11, s0 = row0&(SEQ-1);
        f16x4 pk;
        #pragma unroll
        for (int r=0;r<4;++r) pk[r] = (f16)(v[r]+bz);
        *(f16x4*)(out2 + ((size_t)(b_*NH+hh)*DKH + dk)*SEQ + s0) = pk;
      } else {
        #pragma unroll
        for (int r=0;r<4;++r) {
          size_t o = (size_t)(row0+r)*D_MODEL + col;
          xout[o] = v[r] + bz + resid[o];
        }
      }
    }
  }
}

// ---------------- fused causal attention ----------------
// R14 + FIFO decoupling in pass 2: per tile the order is now
// QK^T -> exp/el -> PV (loads only) -> NT stores. PV's V-fragment loads are
// OLDER than the tile's NT stores in the shared in-order vmcnt FIFO, so PV
// never waits on HBM store drain; stores retire under the next tile's QK^T.

__global__ __launch_bounds__(256) void attn_kernel(
    const f16* __restrict__ qws, const f16* __restrict__ kws, const f16* __restrict__ vTws,
    float* __restrict__ attn, f16* __restrict__ ctx)
{
  __shared__ f16 el[4][32*128];
  const int t = threadIdx.x, w = t>>6, l = t&63;
  const int wg = ((int)blockIdx.x & 7)*64 + ((int)blockIdx.x >> 3);
  const int bh = wg >> 3;
  const int pr = wg & 7;
  const int qtA = pr, qtB = 15 - pr;
  const int fr = l & 15, fg = l >> 4;
  const f16* kp = kws + (size_t)bh*SEQ*DKH;
  const f16* vp = vTws + (size_t)bh*DKH*SEQ;
  const f16* qpA = qws + ((size_t)bh*SEQ + (size_t)qtA*128)*DKH;
  const f16* qpB = qws + ((size_t)bh*SEQ + (size_t)qtB*128)*DKH;
  float* apA = attn + ((size_t)bh*SEQ + (size_t)qtA*128)*SEQ;
  float* apB = attn + ((size_t)bh*SEQ + (size_t)qtB*128)*SEQ;
  f16* elw = (f16*)&el[w][0];
  const int swzx = (fr & 7) << 2;
  const int rbrow = l >> 5;
  const int rbslot = l & 31;

  f16x8 qfA[2][2], qfB[2][2];
  #pragma unroll
  for (int i=0;i<2;++i)
    #pragma unroll
    for (int kc=0;kc<2;++kc) {
      qfA[i][kc] = *(const f16x8*)(qpA + (w*32 + i*16 + fr)*DKH + kc*32 + fg*8);
      qfB[i][kc] = *(const f16x8*)(qpB + (w*32 + i*16 + fr)*DKH + kc*32 + fg*8);
    }

  auto fill_tile = [&](float* apr, int kt2) {
    f32x4 z4 = {0.f,0.f,0.f,0.f};
    #pragma unroll
    for (int i2=0;i2<16;++i2) {
      int idx = t + i2*256;
      int row = idx >> 5, c4 = idx & 31;
      __builtin_nontemporal_store(z4, (f32x4*)(apr + (size_t)row*SEQ + (size_t)kt2*128 + c4*4));
    }
  };
  const int cB = pr;   // fills for B: qtB+1..15 (pr tiles); A: qtA+1..15 (15-pr)

  // ---- pass 1: fused A+B over 0..qtA, solo B over qtA+1..qtB; fills dripped ----
  float psumA[2] = {0.f,0.f}, psumB[2] = {0.f,0.f};
  int u = 0, f = 0;
  const int np1 = qtB + 1;
  auto drip_fills = [&]() {
    while (f*np1 < u*15) {
      if (f < cB) fill_tile(apB, qtB+1+f);
      else        fill_tile(apA, qtA+1+(f-cB));
      ++f;
    }
  };

  for (int kt=0; kt<=qtA; ++kt) {       // fused region: 4 MFMA per kf load
    const f16* kb = kp + (size_t)kt*128*DKH;
    const bool diagA = (kt == qtA);
    #pragma unroll
    for (int jh=0; jh<2; ++jh) {
      f32x4 scB[2][4] = {};
      f32x4 scA[2][4] = {};
      #pragma unroll
      for (int j2=0;j2<4;++j2) {
        const int j = jh*4 + j2;
        #pragma unroll
        for (int kc=0;kc<2;++kc) {
          f16x8 kf = *(const f16x8*)(kb + (j*16+fr)*DKH + kc*32 + fg*8);
          scB[0][j2] = MFMA16(kf, qfB[0][kc], scB[0][j2]);
          scB[1][j2] = MFMA16(kf, qfB[1][kc], scB[1][j2]);
          scA[0][j2] = MFMA16(kf, qfA[0][kc], scA[0][j2]);
          scA[1][j2] = MFMA16(kf, qfA[1][kc], scA[1][j2]);
        }
      }
      #pragma unroll
      for (int i=0;i<2;++i)
        #pragma unroll
        for (int j2=0;j2<4;++j2)
          #pragma unroll
          for (int r=0;r<4;++r) psumB[i] += __expf(scB[i][j2][r]);
      if (diagA) {
        #pragma unroll
        for (int i=0;i<2;++i) {
          int rloc = w*32 + i*16 + fr;
          #pragma unroll
          for (int j2=0;j2<4;++j2)
            #pragma unroll
            for (int r=0;r<4;++r) {
              int cloc = (jh*4+j2)*16 + fg*4 + r;
              if (cloc <= rloc) psumA[i] += __expf(scA[i][j2][r]);
            }
        }
      } else {
        #pragma unroll
        for (int i=0;i<2;++i)
          #pragma unroll
          for (int j2=0;j2<4;++j2)
            #pragma unroll
            for (int r=0;r<4;++r) psumA[i] += __expf(scA[i][j2][r]);
      }
    }
    ++u; drip_fills();
  }

  for (int kt=qtA+1; kt<=qtB; ++kt) {   // solo B region
    const f16* kb = kp + (size_t)kt*128*DKH;
    const bool diagB = (kt == qtB);
    #pragma unroll
    for (int jh=0; jh<2; ++jh) {
      f32x4 sc[2][4] = {};
      #pragma unroll
      for (int j2=0;j2<4;++j2) {
        const int j = jh*4 + j2;
        #pragma unroll
        for (int kc=0;kc<2;++kc) {
          f16x8 kf = *(const f16x8*)(kb + (j*16+fr)*DKH + kc*32 + fg*8);
          sc[0][j2] = MFMA16(kf, qfB[0][kc], sc[0][j2]);
          sc[1][j2] = MFMA16(kf, qfB[1][kc], sc[1][j2]);
        }
      }
      if (diagB) {
        #pragma unroll
        for (int i=0;i<2;++i) {
          int rloc = w*32 + i*16 + fr;
          #pragma unroll
          for (int j2=0;j2<4;++j2)
            #pragma unroll
            for (int r=0;r<4;++r) {
              int cloc = (jh*4+j2)*16 + fg*4 + r;
              if (cloc <= rloc) psumB[i] += __expf(sc[i][j2][r]);
            }
        }
      } else {
        #pragma unroll
        for (int i=0;i<2;++i)
          #pragma unroll
          for (int j2=0;j2<4;++j2)
            #pragma unroll
            for (int r=0;r<4;++r) psumB[i] += __expf(sc[i][j2][r]);
      }
    }
    ++u; drip_fills();
  }

  #pragma unroll
  for (int m=16; m<64; m<<=1) {
    psumA[0] += __shfl_xor(psumA[0], m, 64);
    psumA[1] += __shfl_xor(psumA[1], m, 64);
    psumB[0] += __shfl_xor(psumB[0], m, 64);
    psumB[1] += __shfl_xor(psumB[1], m, 64);
  }
  float rinvA[2] = {1.f/psumA[0], 1.f/psumA[1]};
  float rinvB[2] = {1.f/psumB[0], 1.f/psumB[1]};

  // ---- pass 2: QK^T -> exp/el -> PV -> NT stores (store block moved last) ----
  f32x4 av[2][4];
  auto pass2_tile = [&](int ktv, bool diag, const f16x8 (&qf)[2][2], const float (&rinv)[2], float* apr) {
    const f16* kb = kp + (size_t)ktv*128*DKH;
    #pragma unroll
    for (int jh=0; jh<2; ++jh) {
      f32x4 sc[2][4] = {};
      __builtin_amdgcn_s_setprio(1);
      #pragma unroll
      for (int j2=0;j2<4;++j2) {
        const int j = jh*4 + j2;
        #pragma unroll
        for (int kc=0;kc<2;++kc) {
          f16x8 kf = *(const f16x8*)(kb + (j*16+fr)*DKH + kc*32 + fg*8);
          sc[0][j2] = MFMA16(kf, qf[0][kc], sc[0][j2]);
          sc[1][j2] = MFMA16(kf, qf[1][kc], sc[1][j2]);
        }
      }
      __builtin_amdgcn_s_setprio(0);
      #pragma unroll
      for (int i=0;i<2;++i) {
        const int rloc = w*32 + i*16 + fr;
        #pragma unroll
        for (int j2=0;j2<4;++j2) {
          const int j = jh*4 + j2;
          f16x4 ef;
          #pragma unroll
          for (int r=0;r<4;++r) {
            int cloc = j*16 + fg*4 + r;
            float e = (diag && cloc > rloc) ? 0.f : __expf(sc[i][j2][r]) * rinv[i];
            ef[r] = (f16)e;
          }
          *(f16x4*)(elw + (i*16+fr)*128 + (((j*4+fg) ^ swzx) << 2)) = ef;
        }
      }
    }
    // PV first: V-fragment loads are older than this tile's NT stores in the
    // vmcnt FIFO -> PV never waits on store drain.
    __builtin_amdgcn_s_setprio(1);
    #pragma unroll
    for (int c=0;c<4;++c) {
      f16x8 pf0 = *(const f16x8*)(elw + (fr)*128    + (((c*8+fg*2) ^ swzx) << 2));
      f16x8 pf1 = *(const f16x8*)(elw + (16+fr)*128 + (((c*8+fg*2) ^ swzx) << 2));
      #pragma unroll
      for (int j2=0;j2<4;++j2) {
        f16x8 vf = *(const f16x8*)(vp + (j2*16+fr)*SEQ + ktv*128 + c*32 + fg*8);
        av[0][j2] = MFMA16(vf, pf0, av[0][j2]);
        av[1][j2] = MFMA16(vf, pf1, av[1][j2]);
      }
    }
    __builtin_amdgcn_s_setprio(0);
    // NT prob stores last; they drain under the next tile's QK^T.
    {
      float* apk = apr + (size_t)(w*32)*SEQ + (size_t)ktv*128;
      #pragma unroll
      for (int p=0;p<16;++p) {
        int row = p*2 + rbrow;
        f16x4 pv4 = *(const f16x4*)(elw + row*128 + ((rbslot ^ ((row&7)<<2)) << 2));
        f32x4 o4; o4[0]=(float)pv4[0]; o4[1]=(float)pv4[1]; o4[2]=(float)pv4[2]; o4[3]=(float)pv4[3];
        __builtin_nontemporal_store(o4, (f32x4*)(apk + (size_t)row*SEQ + rbslot*4));
      }
    }
  };
  auto ctx_store = [&](int qtv) {
    const int b_ = bh >> 4, hh = bh & 15;
    #pragma unroll
    for (int i=0;i<2;++i) {
      size_t rowoff = ((size_t)b_*SEQ + (size_t)qtv*128 + w*32 + i*16 + fr) * D_MODEL + hh*DKH;
      #pragma unroll
      for (int j2=0;j2<4;++j2) {
        f16x4 pk;
        #pragma unroll
        for (int r=0;r<4;++r) pk[r] = (f16)av[i][j2][r];
        *(f16x4*)(ctx + rowoff + j2*16 + fg*4) = pk;
      }
    }
  };

  #pragma unroll
  for (int i=0;i<2;++i)
    #pragma unroll
    for (int j2=0;j2<4;++j2) av[i][j2] = (f32x4){0.f,0.f,0.f,0.f};
  for (int kt=0; kt<=qtA; ++kt) pass2_tile(kt, kt==qtA, qfA, rinvA, apA);
  ctx_store(qtA);

  #pragma unroll
  for (int i=0;i<2;++i)
    #pragma unroll
    for (int j2=0;j2<4;++j2) av[i][j2] = (f32x4){0.f,0.f,0.f,0.f};
  for (int kt=0; kt<=qtB; ++kt) pass2_tile(kt, kt==qtB, qfB, rinvB, apB);
  ctx_store(qtB);
}

// ---------------- LayerNorm ----------------

__global__ __launch_bounds__(256) void ln_kernel(const float* __restrict__ x,
    const float* __restrict__ gamma, const float* __restrict__ beta, float* __restrict__ y)
{
  __shared__ float red[4];
  __shared__ float red2[4];
  const int t = threadIdx.x, w = t>>6, l = t&63;
  const size_t row = blockIdx.x;
  float4 v = ((const float4*)(x + row*D_MODEL))[t];
  float s = v.x+v.y+v.z+v.w;
  #pragma unroll
  for (int m=1;m<64;m<<=1) s += __shfl_xor(s, m, 64);
  if (l==0) red[w] = s;
  __syncthreads();
  float mu = (red[0]+red[1]+red[2]+red[3]) * (1.f/D_MODEL);
  float dx=v.x-mu, dy=v.y-mu, dz=v.z-mu, dw=v.w-mu;
  float q = dx*dx+dy*dy+dz*dz+dw*dw;
  #pragma unroll
  for (int m=1;m<64;m<<=1) q += __shfl_xor(q, m, 64);
  if (l==0) red2[w] = q;
  __syncthreads();
  float var = (red2[0]+red2[1]+red2[2]+red2[3]) * (1.f/D_MODEL);
  float rs = rsqrtf(var + 1e-5f);
  float4 g  = ((const float4*)gamma)[t];
  float4 bb = ((const float4*)beta)[t];
  float4 o;
  o.x = dx*rs*g.x + bb.x;
  o.y = dy*rs*g.y + bb.y;
  o.z = dz*rs*g.z + bb.z;
  o.w = dw*rs*g.w + bb.w;
  ((float4*)(y + row*D_MODEL))[t] = o;
}

// ---------------- launch ----------------

extern "C" void kernel_launch(void* const* d_in, const int* in_sizes, int n_in,
                              void* d_out, int out_size, void* d_ws, size_t ws_size,
                              hipStream_t stream)
{
  const float* Q  = (const float*)d_in[0];
  const float* K  = (const float*)d_in[1];
  const float* V  = (const float*)d_in[2];
  const float* Wq = (const float*)d_in[4];
  const float* bq = (const float*)d_in[5];
  const float* Wk = (const float*)d_in[6];
  const float* bk = (const float*)d_in[7];
  const float* Wv = (const float*)d_in[8];
  const float* bv = (const float*)d_in[9];
  const float* Wo = (const float*)d_in[10];
  const float* bo = (const float*)d_in[11];
  const float* gam= (const float*)d_in[12];
  const float* bet= (const float*)d_in[13];

  float* y    = (float*)d_out;
  float* attn = y + (size_t)ROWS*D_MODEL;

  char* ws = (char*)d_ws;
  const size_t SZ = (size_t)ROWS*D_MODEL*sizeof(f16);  // 16 MiB per f16 matrix
  f16* ctx   = (f16*)ws;                 // [0, SZ)
  float* xb  = (float*)(ws + SZ);        // [SZ, 3SZ) fp32 x
  f16* WT    = (f16*)(ws + 3*SZ);        // 4 x 2 MiB transposed f16 weights
  f16* qws   = (f16*)(ws + 3*SZ + ((size_t)4*D_MODEL*D_MODEL*sizeof(f16)));
  f16* kws   = (f16*)((char*)qws + SZ);
  f16* vT    = (f16*)((char*)kws + SZ);

  cvt_w_kernel<<<dim3(4096,1,4), 256, 0, stream>>>(Wq, Wk, Wv, Wo, WT);
  gemm128<1><<<1536, 256, 0, stream>>>(Q, K, V, WT, bq, bk, bv, qws, kws, vT, nullptr, nullptr, 0);
  attn_kernel<<<512, 256, 0, stream>>>(qws, kws, vT, attn, ctx);
  gemm128<0><<<512, 256, 0, stream>>>(ctx, nullptr, nullptr, WT, bo, bo, bo, nullptr, nullptr, nullptr, Q, xb, 3);
  ln_kernel<<<8192, 256, 0, stream>>>(xb, gam, bet, y);
}

// Round 16
// 427.547 us; speedup vs baseline: 1.0664x; 1.0664x over previous
//
#include <hip/hip_runtime.h>

#define D_MODEL 1024
#define NH 16
#define DKH 64
#define SEQ 2048
#define BATCH 4
#define ROWS (BATCH*SEQ)

typedef _Float16 f16;
typedef _Float16 f16x4 __attribute__((ext_vector_type(4)));
typedef _Float16 f16x8 __attribute__((ext_vector_type(8)));
typedef float f32x4 __attribute__((ext_vector_type(4)));

#define MFMA16(a,b,c) __builtin_amdgcn_mfma_f32_16x16x32_f16((a),(b),(c),0,0,0)
#define CFENCE() asm volatile("" ::: "memory")

__device__ __forceinline__ void gload16(const void* g, void* l) {
  __builtin_amdgcn_global_load_lds((const __attribute__((address_space(1))) void*)g,
                                   (__attribute__((address_space(3))) void*)l,
                                   16, 0, 0);
}

// ---------------- weight transpose/convert ----------------

__global__ __launch_bounds__(256) void cvt_w_kernel(const float* __restrict__ Wq,
    const float* __restrict__ Wk, const float* __restrict__ Wv, const float* __restrict__ Wo,
    f16* __restrict__ dst)
{
  const float* W = (blockIdx.z==0)?Wq:(blockIdx.z==1)?Wk:(blockIdx.z==2)?Wv:Wo;
  f16* d = dst + (size_t)blockIdx.z * ((size_t)D_MODEL*D_MODEL);
  int idx = blockIdx.x*256 + threadIdx.x;
  int k = idx>>10, n = idx&1023;
  d[(size_t)n*D_MODEL + k] = (f16)W[idx];   // store W^T: [n][k]
}

// ---------------- 128x128 MFMA GEMM (R14-identical) ----------------

template<int AF32>
__global__ __launch_bounds__(256) void gemm128(
    const void* __restrict__ A0, const void* __restrict__ A1, const void* __restrict__ A2,
    const f16* __restrict__ WTbase,
    const float* __restrict__ bias0, const float* __restrict__ bias1, const float* __restrict__ bias2,
    f16* __restrict__ out0, f16* __restrict__ out1, f16* __restrict__ out2,
    const float* __restrict__ resid, float* __restrict__ xout, int modeBase)
{
  __shared__ __align__(128) char ldsb[49152];
  const int t = threadIdx.x, w = t>>6, l = t&63;
  const int nwg = (int)gridDim.x;
  const int wg = ((int)blockIdx.x & 7) * (nwg >> 3) + ((int)blockIdx.x >> 3);
  const int z  = wg >> 9;            // 512 blocks per mode
  const int r2 = wg & 511;
  const int bm = r2 >> 3, bn = r2 & 7;
  const int mode = modeBase + z;
  const f16* WT = WTbase + (size_t)mode * ((size_t)D_MODEL*D_MODEL);
  const float* bias = (mode==0)?bias0:(mode==1)?bias1:(mode==2)?bias2:bias0;
  const int wm = w>>1, wn = w&1;
  const int lr = l>>2, lc = l&3, fr = l&15, fg = l>>4;
  f32x4 acc[4][4] = {};
  const char* Bb = (const char*)(WT + (size_t)bn*128*D_MODEL);

#define BAR_FENCED() do { __builtin_amdgcn_s_barrier(); CFENCE(); } while(0)

  if constexpr (AF32) {
    const float* A32 = (const float*)((z==0)?A0:(z==1)?A1:A2);
    const char* Ag = (const char*)A32 + ((size_t)(bm*128 + (t>>3)) * 4096)
                     + (size_t)(((t&7) ^ ((t>>3)&7)) << 4);
    const int su0 = (((fg*2)   ^ (fr&7)) << 4);
    const int su1 = (((fg*2+1) ^ (fr&7)) << 4);

#define STAGEA32(bufv, ktv) do { \
    _Pragma("unroll") \
    for (int cc=0; cc<4; ++cc) \
      gload16(Ag + (size_t)cc*131072 + (size_t)(ktv)*128, ldsb + (bufv)*16384 + cc*4096 + t*16); \
  } while(0)

#define STAGEB32(bufv, ktv) do { \
    char* Bd = ldsb + 32768 + (bufv)*8192; \
    _Pragma("unroll") \
    for (int cc=0; cc<2; ++cc) { \
      int r0 = w*32 + cc*16; \
      gload16(Bb + (size_t)(r0+lr)*2048 + (ktv)*64 + lc*16, Bd + r0*64); \
    } \
  } while(0)

#define COMPUTE32(bufv) do { \
    const char* Abl = ldsb + (bufv)*16384; \
    const f16* Bc = (const f16*)(ldsb + 32768 + (bufv)*8192); \
    f16x8 a[4], b[4]; \
    _Pragma("unroll") \
    for (int i=0;i<4;++i) { \
      const char* rb = Abl + (wm*64 + i*16 + fr)*128; \
      f32x4 lo = *(const f32x4*)(rb + su0); \
      f32x4 hi = *(const f32x4*)(rb + su1); \
      f16x8 t8; \
      _Pragma("unroll") \
      for (int m2=0;m2<4;++m2) { t8[m2] = (f16)lo[m2]; t8[4+m2] = (f16)hi[m2]; } \
      a[i] = t8; \
    } \
    _Pragma("unroll") \
    for (int j=0;j<4;++j) b[j] = *(const f16x8*)(Bc + (wn*64+j*16+fr)*32 + fg*8); \
    _Pragma("unroll") \
    for (int i=0;i<4;++i) \
      _Pragma("unroll") \
      for (int j=0;j<4;++j) \
        acc[i][j] = MFMA16(a[i], b[j], acc[i][j]); \
  } while(0)

    STAGEA32(0, 0); STAGEB32(0, 0);
    CFENCE();
    for (int kt=0; kt<31; ++kt) {
      const int cur = kt & 1;
      STAGEA32(cur^1, kt+1);
      STAGEB32(cur^1, kt+1);
      asm volatile("s_waitcnt vmcnt(6)" ::: "memory");
      BAR_FENCED();
      COMPUTE32(cur);
      CFENCE();
      BAR_FENCED();
    }
    asm volatile("s_waitcnt vmcnt(0)" ::: "memory");
    BAR_FENCED();
    COMPUTE32(1);

#undef STAGEA32
#undef STAGEB32
#undef COMPUTE32
  } else {
    const char* Ab = (const char*)((const f16*)A0 + (size_t)bm*128*D_MODEL);

#define STAGE16(bufv, ktv) do { \
    char* Ad = ldsb + (bufv)*8192; \
    char* Bd = ldsb + 24576 + (bufv)*8192; \
    _Pragma("unroll") \
    for (int cc=0; cc<2; ++cc) { \
      int r0 = w*32 + cc*16; \
      gload16(Ab + (size_t)(r0+lr)*2048 + (ktv)*64 + lc*16, Ad + r0*64); \
      gload16(Bb + (size_t)(r0+lr)*2048 + (ktv)*64 + lc*16, Bd + r0*64); \
    } \
  } while(0)

#define COMPUTE16(bufv) do { \
    const f16* Ac = (const f16*)(ldsb + (bufv)*8192); \
    const f16* Bc = (const f16*)(ldsb + 24576 + (bufv)*8192); \
    f16x8 a[4], b[4]; \
    _Pragma("unroll") \
    for (int i=0;i<4;++i) a[i] = *(const f16x8*)(Ac + (wm*64+i*16+fr)*32 + fg*8); \
    _Pragma("unroll") \
    for (int j=0;j<4;++j) b[j] = *(const f16x8*)(Bc + (wn*64+j*16+fr)*32 + fg*8); \
    _Pragma("unroll") \
    for (int i=0;i<4;++i) \
      _Pragma("unroll") \
      for (int j=0;j<4;++j) \
        acc[i][j] = MFMA16(a[i], b[j], acc[i][j]); \
  } while(0)

    STAGE16(0, 0); STAGE16(1, 1);
    CFENCE();
    for (int kt=0; kt<30; ++kt) {
      STAGE16((kt+2)%3, kt+2);
      asm volatile("s_waitcnt vmcnt(8)" ::: "memory");
      BAR_FENCED();
      COMPUTE16(kt%3);
      CFENCE();
      BAR_FENCED();
    }
    asm volatile("s_waitcnt vmcnt(4)" ::: "memory");
    BAR_FENCED();
    COMPUTE16(0);     // kt=30
    CFENCE();
    BAR_FENCED();
    asm volatile("s_waitcnt vmcnt(0)" ::: "memory");
    BAR_FENCED();
    COMPUTE16(1);     // kt=31

#undef STAGE16
#undef COMPUTE16
  }

#undef BAR_FENCED

  #pragma unroll
  for (int j=0;j<4;++j) {
    int col = bn*128 + wn*64 + j*16 + fr;
    float bz = bias[col];
    #pragma unroll
    for (int i=0;i<4;++i) {
      int row0 = bm*128 + wm*64 + i*16 + fg*4;
      f32x4 v = acc[i][j];
      if (mode==0) {
        int hh = col>>6, dk = col&63;
        #pragma unroll
        for (int r=0;r<4;++r) {
          int row = row0+r; int b_ = row>>11, s = row&(SEQ-1);
          out0[((size_t)(b_*NH+hh)*SEQ + s)*DKH + dk] = (f16)((v[r]+bz)*0.125f);
        }
      } else if (mode==1) {
        int hh = col>>6, dk = col&63;
        #pragma unroll
        for (int r=0;r<4;++r) {
          int row = row0+r; int b_ = row>>11, s = row&(SEQ-1);
          out1[((size_t)(b_*NH+hh)*SEQ + s)*DKH + dk] = (f16)(v[r]+bz);
        }
      } else if (mode==2) {
        int hh = col>>6, dk = col&63;
        int b_ = row0>>11, s0 = row0&(SEQ-1);
        f16x4 pk;
        #pragma unroll
        for (int r=0;r<4;++r) pk[r] = (f16)(v[r]+bz);
        *(f16x4*)(out2 + ((size_t)(b_*NH+hh)*DKH + dk)*SEQ + s0) = pk;
      } else {
        #pragma unroll
        for (int r=0;r<4;++r) {
          size_t o = (size_t)(row0+r)*D_MODEL + col;
          xout[o] = v[r] + bz + resid[o];
        }
      }
    }
  }
}

// ---------------- fused causal attention: 512-thread pair-blocks, wave-group split ----------------
// Waves 0-3 own tile A (qtA=pr), waves 4-7 own tile B (qtB=15-pr). Per-wave reuse
// unchanged (32 q-rows, 2 MFMA per K-fragment load); occupancy doubles to 16
// waves/CU (2 blocks x 8 waves). Group-balanced: A = (pr+1) computes + (15-pr)
// fills = 16 units; B = (16-pr) computes + pr fills = 16. No cross-group barriers.

__global__ __launch_bounds__(512, 2) void attn_kernel(
    const f16* __restrict__ qws, const f16* __restrict__ kws, const f16* __restrict__ vTws,
    float* __restrict__ attn, f16* __restrict__ ctx)
{
  __shared__ f16 el[8][32*128];     // 8 KB per wave, 64 KB total
  const int t = threadIdx.x, w = t>>6, l = t&63;
  const int wg = ((int)blockIdx.x & 7)*64 + ((int)blockIdx.x >> 3);
  const int bh = wg >> 3;
  const int pr = wg & 7;
  const int grp = w >> 2;            // 0 = tile A, 1 = tile B
  const int wl = w & 3;              // wave within group
  const int qt = grp ? (15 - pr) : pr;
  const int fr = l & 15, fg = l >> 4;
  const f16* kp = kws + (size_t)bh*SEQ*DKH;
  const f16* vp = vTws + (size_t)bh*DKH*SEQ;
  const f16* qp = qws + ((size_t)bh*SEQ + (size_t)qt*128)*DKH;
  float* ap = attn + ((size_t)bh*SEQ + (size_t)qt*128)*SEQ;
  f16* elw = (f16*)&el[w][0];
  const int swzx = (fr & 7) << 2;
  const int rbrow = l >> 5;
  const int rbslot = l & 31;
  const int tg = wl*64 + l;          // group-local thread id (0..255)

  // Q fragments for this wave's 32 rows of its tile
  f16x8 qf[2][2];
  #pragma unroll
  for (int i=0;i<2;++i)
    #pragma unroll
    for (int kc=0;kc<2;++kc)
      qf[i][kc] = *(const f16x8*)(qp + (wl*32 + i*16 + fr)*DKH + kc*32 + fg*8);

  // group fill: 4 waves cover a 128x128 f32 tile
  auto fill_tile = [&](int kt2) {
    f32x4 z4 = {0.f,0.f,0.f,0.f};
    #pragma unroll
    for (int i2=0;i2<16;++i2) {
      int idx = tg + i2*256;
      int row = idx >> 5, c4 = idx & 31;
      __builtin_nontemporal_store(z4, (f32x4*)(ap + (size_t)row*SEQ + (size_t)kt2*128 + c4*4));
    }
  };
  const int nComp = qt + 1;          // compute slices for this group
  const int nFill = 15 - qt;         // fill tiles for this group (own upper tiles)

  // ---- pass 1: row sums of exp, fills dripped ----
  float psum[2] = {0.f, 0.f};
  int f = 0;
  for (int kt=0; kt<=qt; ++kt) {
    const f16* kb = kp + (size_t)kt*128*DKH;
    const bool diag = (kt == qt);
    #pragma unroll
    for (int jh=0; jh<2; ++jh) {
      f32x4 sc[2][4] = {};
      #pragma unroll
      for (int j2=0;j2<4;++j2) {
        const int j = jh*4 + j2;
        #pragma unroll
        for (int kc=0;kc<2;++kc) {
          f16x8 kf = *(const f16x8*)(kb + (j*16+fr)*DKH + kc*32 + fg*8);
          sc[0][j2] = MFMA16(kf, qf[0][kc], sc[0][j2]);
          sc[1][j2] = MFMA16(kf, qf[1][kc], sc[1][j2]);
        }
      }
      if (diag) {
        #pragma unroll
        for (int i=0;i<2;++i) {
          int rloc = wl*32 + i*16 + fr;
          #pragma unroll
          for (int j2=0;j2<4;++j2)
            #pragma unroll
            for (int r=0;r<4;++r) {
              int cloc = (jh*4+j2)*16 + fg*4 + r;
              if (cloc <= rloc) psum[i] += __expf(sc[i][j2][r]);
            }
        }
      } else {
        #pragma unroll
        for (int i=0;i<2;++i)
          #pragma unroll
          for (int j2=0;j2<4;++j2)
            #pragma unroll
            for (int r=0;r<4;++r) psum[i] += __expf(sc[i][j2][r]);
      }
    }
    // drip this group's fills between compute slices
    while (f*nComp < (kt+1)*nFill) { fill_tile(qt+1+f); ++f; }
  }
  while (f < nFill) { fill_tile(qt+1+f); ++f; }

  #pragma unroll
  for (int m=16; m<64; m<<=1) {
    psum[0] += __shfl_xor(psum[0], m, 64);
    psum[1] += __shfl_xor(psum[1], m, 64);
  }
  float rinv[2] = {1.f/psum[0], 1.f/psum[1]};

  // ---- pass 2: QK^T -> exp/el -> PV -> NT stores ----
  f32x4 av[2][4];
  #pragma unroll
  for (int i=0;i<2;++i)
    #pragma unroll
    for (int j2=0;j2<4;++j2) av[i][j2] = (f32x4){0.f,0.f,0.f,0.f};

  for (int kt=0; kt<=qt; ++kt) {
    const f16* kb = kp + (size_t)kt*128*DKH;
    const bool diag = (kt == qt);
    #pragma unroll
    for (int jh=0; jh<2; ++jh) {
      f32x4 sc[2][4] = {};
      __builtin_amdgcn_s_setprio(1);
      #pragma unroll
      for (int j2=0;j2<4;++j2) {
        const int j = jh*4 + j2;
        #pragma unroll
        for (int kc=0;kc<2;++kc) {
          f16x8 kf = *(const f16x8*)(kb + (j*16+fr)*DKH + kc*32 + fg*8);
          sc[0][j2] = MFMA16(kf, qf[0][kc], sc[0][j2]);
          sc[1][j2] = MFMA16(kf, qf[1][kc], sc[1][j2]);
        }
      }
      __builtin_amdgcn_s_setprio(0);
      #pragma unroll
      for (int i=0;i<2;++i) {
        const int rloc = wl*32 + i*16 + fr;
        #pragma unroll
        for (int j2=0;j2<4;++j2) {
          const int j = jh*4 + j2;
          f16x4 ef;
          #pragma unroll
          for (int r=0;r<4;++r) {
            int cloc = j*16 + fg*4 + r;
            float e = (diag && cloc > rloc) ? 0.f : __expf(sc[i][j2][r]) * rinv[i];
            ef[r] = (f16)e;
          }
          *(f16x4*)(elw + (i*16+fr)*128 + (((j*4+fg) ^ swzx) << 2)) = ef;
        }
      }
    }
    // PV before stores (older in vmcnt FIFO than this tile's NT stores)
    __builtin_amdgcn_s_setprio(1);
    #pragma unroll
    for (int c=0;c<4;++c) {
      f16x8 pf0 = *(const f16x8*)(elw + (fr)*128    + (((c*8+fg*2) ^ swzx) << 2));
      f16x8 pf1 = *(const f16x8*)(elw + (16+fr)*128 + (((c*8+fg*2) ^ swzx) << 2));
      #pragma unroll
      for (int j2=0;j2<4;++j2) {
        f16x8 vf = *(const f16x8*)(vp + (j2*16+fr)*SEQ + kt*128 + c*32 + fg*8);
        av[0][j2] = MFMA16(vf, pf0, av[0][j2]);
        av[1][j2] = MFMA16(vf, pf1, av[1][j2]);
      }
    }
    __builtin_amdgcn_s_setprio(0);
    // full-line NT prob stores via LDS readback
    {
      float* apk = ap + (size_t)(wl*32)*SEQ + (size_t)kt*128;
      #pragma unroll
      for (int p=0;p<16;++p) {
        int row = p*2 + rbrow;
        f16x4 pv4 = *(const f16x4*)(elw + row*128 + ((rbslot ^ ((row&7)<<2)) << 2));
        f32x4 o4; o4[0]=(float)pv4[0]; o4[1]=(float)pv4[1]; o4[2]=(float)pv4[2]; o4[3]=(float)pv4[3];
        __builtin_nontemporal_store(o4, (f32x4*)(apk + (size_t)row*SEQ + rbslot*4));
      }
    }
  }

  // ctx epilogue
  {
    const int b_ = bh >> 4, hh = bh & 15;
    #pragma unroll
    for (int i=0;i<2;++i) {
      size_t rowoff = ((size_t)b_*SEQ + (size_t)qt*128 + wl*32 + i*16 + fr) * D_MODEL + hh*DKH;
      #pragma unroll
      for (int j2=0;j2<4;++j2) {
        f16x4 pk;
        #pragma unroll
        for (int r=0;r<4;++r) pk[r] = (f16)av[i][j2][r];
        *(f16x4*)(ctx + rowoff + j2*16 + fg*4) = pk;
      }
    }
  }
}

// ---------------- LayerNorm ----------------

__global__ __launch_bounds__(256) void ln_kernel(const float* __restrict__ x,
    const float* __restrict__ gamma, const float* __restrict__ beta, float* __restrict__ y)
{
  __shared__ float red[4];
  __shared__ float red2[4];
  const int t = threadIdx.x, w = t>>6, l = t&63;
  const size_t row = blockIdx.x;
  float4 v = ((const float4*)(x + row*D_MODEL))[t];
  float s = v.x+v.y+v.z+v.w;
  #pragma unroll
  for (int m=1;m<64;m<<=1) s += __shfl_xor(s, m, 64);
  if (l==0) red[w] = s;
  __syncthreads();
  float mu = (red[0]+red[1]+red[2]+red[3]) * (1.f/D_MODEL);
  float dx=v.x-mu, dy=v.y-mu, dz=v.z-mu, dw=v.w-mu;
  float q = dx*dx+dy*dy+dz*dz+dw*dw;
  #pragma unroll
  for (int m=1;m<64;m<<=1) q += __shfl_xor(q, m, 64);
  if (l==0) red2[w] = q;
  __syncthreads();
  float var = (red2[0]+red2[1]+red2[2]+red2[3]) * (1.f/D_MODEL);
  float rs = rsqrtf(var + 1e-5f);
  float4 g  = ((const float4*)gamma)[t];
  float4 bb = ((const float4*)beta)[t];
  float4 o;
  o.x = dx*rs*g.x + bb.x;
  o.y = dy*rs*g.y + bb.y;
  o.z = dz*rs*g.z + bb.z;
  o.w = dw*rs*g.w + bb.w;
  ((float4*)(y + row*D_MODEL))[t] = o;
}

// ---------------- launch ----------------

extern "C" void kernel_launch(void* const* d_in, const int* in_sizes, int n_in,
                              void* d_out, int out_size, void* d_ws, size_t ws_size,
                              hipStream_t stream)
{
  const float* Q  = (const float*)d_in[0];
  const float* K  = (const float*)d_in[1];
  const float* V  = (const float*)d_in[2];
  const float* Wq = (const float*)d_in[4];
  const float* bq = (const float*)d_in[5];
  const float* Wk = (const float*)d_in[6];
  const float* bk = (const float*)d_in[7];
  const float* Wv = (const float*)d_in[8];
  const float* bv = (const float*)d_in[9];
  const float* Wo = (const float*)d_in[10];
  const float* bo = (const float*)d_in[11];
  const float* gam= (const float*)d_in[12];
  const float* bet= (const float*)d_in[13];

  float* y    = (float*)d_out;
  float* attn = y + (size_t)ROWS*D_MODEL;

  char* ws = (char*)d_ws;
  const size_t SZ = (size_t)ROWS*D_MODEL*sizeof(f16);  // 16 MiB per f16 matrix
  f16* ctx   = (f16*)ws;                 // [0, SZ)
  float* xb  = (float*)(ws + SZ);        // [SZ, 3SZ) fp32 x
  f16* WT    = (f16*)(ws + 3*SZ);        // 4 x 2 MiB transposed f16 weights
  f16* qws   = (f16*)(ws + 3*SZ + ((size_t)4*D_MODEL*D_MODEL*sizeof(f16)));
  f16* kws   = (f16*)((char*)qws + SZ);
  f16* vT    = (f16*)((char*)kws + SZ);

  cvt_w_kernel<<<dim3(4096,1,4), 256, 0, stream>>>(Wq, Wk, Wv, Wo, WT);
  gemm128<1><<<1536, 256, 0, stream>>>(Q, K, V, WT, bq, bk, bv, qws, kws, vT, nullptr, nullptr, 0);
  attn_kernel<<<512, 512, 0, stream>>>(qws, kws, vT, attn, ctx);
  gemm128<0><<<512, 256, 0, stream>>>(ctx, nullptr, nullptr, WT, bo, bo, bo, nullptr, nullptr, nullptr, Q, xb, 3);
  ln_kernel<<<8192, 256, 0, stream>>>(xb, gam, bet, y);
}